// Round 2
// baseline (174.233 us; speedup 1.0000x reference)
//
#include <hip/hip_runtime.h>

// Bilateral filter, fixed shape: x[16,3,512,512] fp32, K=5, pad=2 reflect.
// sigma_color = sigma_space = 0.15*5+0.35 = 1.1  ->  coef = -1/(2*1.21)
// w_color and w_space normalizations cancel in the ratio, so use unnormalized
// gaussians. Space weight folded into the exponent:
//   ks_i*ks_j*exp(coef*d^2) = exp2(coef2*(d^2 + oi^2 + oj^2)),
//   coef2 = coef * log2(e).

constexpr int H_ = 512;
constexpr int W_ = 512;
constexpr int PAD = 2;

__global__ __launch_bounds__(256) void bilateral_kernel(
    const float* __restrict__ x,
    float* __restrict__ out,
    int total)
{
    int idx = blockIdx.x * 256 + threadIdx.x;
    if (idx >= total) return;

    int hw = idx & (H_ * W_ - 1);
    int h  = hw >> 9;          // W_ = 512
    int w  = hw & (W_ - 1);
    int base = idx - hw;       // (b*C + c) * H*W

    const float coef2 = -1.4426950408889634f / 2.42f;  // -log2(e)/(2*sigma^2)

    float c = x[idx];

    // Branchless reflect (pad=2 <= H-1, single reflection suffices):
    // reflect(r) = min(abs(r), 2*(H-1)-r)
    int rbase[5];
    int cofs[5];
    float o2[5];
#pragma unroll
    for (int i = 0; i < 5; ++i) {
        int r = h + i - PAD;
        r = min(abs(r), 2 * (H_ - 1) - r);
        rbase[i] = base + r * W_;
        int cc = w + i - PAD;
        cofs[i] = min(abs(cc), 2 * (W_ - 1) - cc);
        float o = (float)(i - PAD);
        o2[i] = o * o;
    }

    float num = 0.0f, den = 0.0f;
#pragma unroll
    for (int i = 0; i < 5; ++i) {
#pragma unroll
        for (int j = 0; j < 5; ++j) {
            float p = x[rbase[i] + cofs[j]];
            float d = p - c;
            float sij = o2[i] + o2[j];              // compile-time constant
            float arg = fmaf(d, d, sij) * coef2;
            float wgt = exp2f(arg);                  // v_exp_f32
            num = fmaf(wgt, p, num);
            den += wgt;
        }
    }

    out[idx] = num / den;
}

extern "C" void kernel_launch(void* const* d_in, const int* in_sizes, int n_in,
                              void* d_out, int out_size, void* d_ws, size_t ws_size,
                              hipStream_t stream)
{
    const float* x = (const float*)d_in[0];
    float* out = (float*)d_out;
    int total = in_sizes[0];
    int blocks = (total + 255) / 256;
    bilateral_kernel<<<blocks, 256, 0, stream>>>(x, out, total);
}

// Round 3
// 138.474 us; speedup vs baseline: 1.2582x; 1.2582x over previous
//
#include <hip/hip_runtime.h>

// Bilateral filter, fixed shape: x[16,3,512,512] fp32, K=5, pad=2 reflect.
// sigma_color = sigma_space = 1.1 -> coef = -1/(2*1.21); both normalizations
// cancel in the ratio. Space weight folded into the exponent:
//   w = exp2(coef2 * (d^2 + oi^2 + oj^2)),  coef2 = -log2(e)/2.42.
//
// One thread = 4 consecutive pixels (aligned quad). Per kernel row we load the
// 8-float window [w0-2 .. w0+5] as float2+float4+float2 with clamped addresses;
// column reflect needs only 2 cndmask fixups (verified):
//   w0==0  : Wf[0] (col -2 -> x[2])  = Wf[4]; Wf[1]=x[1] already correct.
//   w0==508: Wf[7] (col 513 -> x[509]) = Wf[3]; Wf[6]=x[510] already correct.
// Row reflect: r = min(abs(r), 2*(H-1)-r).

constexpr int H_ = 512;
constexpr int W_ = 512;

__global__ __launch_bounds__(256) void bilateral_kernel(
    const float* __restrict__ x,
    float* __restrict__ out,
    int nquads)
{
    int t = blockIdx.x * 256 + threadIdx.x;
    if (t >= nquads) return;

    int w0   = (t & 127) << 2;       // quad start column (multiple of 4)
    int row  = t >> 7;               // row among B*C*H rows
    int h    = row & (H_ - 1);
    int pbase = (row - h) * W_;      // plane * H*W  (since row = plane*H + h)

    const float coef2 = -0.59615498f;  // -log2(e)/(2*1.21)

    // row bases with reflect
    int rb[5];
#pragma unroll
    for (int i = 0; i < 5; ++i) {
        int r = h + i - 2;
        r = min(abs(r), 2 * (H_ - 1) - r);
        rb[i] = pbase + r * W_;
    }

    int aL = max(w0 - 2, 0);
    int aR = min(w0 + 4, W_ - 2);
    bool bL = (w0 == 0);
    bool bR = (w0 == W_ - 4);

    // center pixels (row i=2 never reflects: min(abs(h),1022-h)==h)
    float4 cc = *(const float4*)(x + rb[2] + w0);
    float c[4] = {cc.x, cc.y, cc.z, cc.w};

    float num[4] = {0.f, 0.f, 0.f, 0.f};
    float den[4] = {0.f, 0.f, 0.f, 0.f};

#pragma unroll
    for (int i = 0; i < 5; ++i) {
        const float* rp = x + rb[i];
        float2 l2 = *(const float2*)(rp + aL);
        float4 c4 = *(const float4*)(rp + w0);
        float2 r2 = *(const float2*)(rp + aR);
        float Wf[8] = {l2.x, l2.y, c4.x, c4.y, c4.z, c4.w, r2.x, r2.y};
        Wf[0] = bL ? Wf[4] : Wf[0];
        Wf[7] = bR ? Wf[3] : Wf[7];

#pragma unroll
        for (int q = 0; q < 4; ++q) {
            float cq = c[q];
#pragma unroll
            for (int j = 0; j < 5; ++j) {
                float p = Wf[q + j];
                float d = p - cq;
                float sij = (float)((i - 2) * (i - 2) + (j - 2) * (j - 2));
                float arg = fmaf(d, d, sij) * coef2;
                float wgt = __builtin_amdgcn_exp2f(arg);
                num[q] = fmaf(wgt, p, num[q]);
                den[q] += wgt;
            }
        }
    }

    float4 o;
    o.x = num[0] * __builtin_amdgcn_rcpf(den[0]);
    o.y = num[1] * __builtin_amdgcn_rcpf(den[1]);
    o.z = num[2] * __builtin_amdgcn_rcpf(den[2]);
    o.w = num[3] * __builtin_amdgcn_rcpf(den[3]);
    *(float4*)(out + rb[2] + w0) = o;
}

extern "C" void kernel_launch(void* const* d_in, const int* in_sizes, int n_in,
                              void* d_out, int out_size, void* d_ws, size_t ws_size,
                              hipStream_t stream)
{
    const float* x = (const float*)d_in[0];
    float* out = (float*)d_out;
    int nquads = in_sizes[0] >> 2;   // 3,145,728 quad-threads
    int blocks = (nquads + 255) / 256;
    bilateral_kernel<<<blocks, 256, 0, stream>>>(x, out, nquads);
}

// Round 4
// 137.215 us; speedup vs baseline: 1.2698x; 1.0092x over previous
//
#include <hip/hip_runtime.h>

// Bilateral filter, fixed shape: x[16,3,512,512] fp32, K=5, pad=2 reflect.
// sigma_color = sigma_space = 1.1; both normalizations cancel in the ratio.
// Weight folded to one exp2: w = exp2(coef2*d^2 + coef2*sij), coef2=-log2(e)/2.42,
// coef2*sij is a compile-time constant per tap.
//
// One thread = 4x4 pixel tile. Loads 8 row-windows [w0-2..w0+5] (float2+float4+
// float2, clamped addresses); column reflect via 2 cndmask fixups per row
// (verified in R2/R3):
//   w0==0  : Wf[0] (col -2 -> x[2])   = Wf[4]
//   w0==508: Wf[7] (col 513 -> x[509]) = Wf[3]
// Row reflect: r = min(abs(r), 2*(H-1)-r).
//
// __launch_bounds__(256,3): min 3 waves/SIMD (~170 VGPR cap) so the compiler
// can hoist all 24 loads + hold the 64-float window in registers. R3's
// VGPR=36 (compiler chasing 8 waves/SIMD) was the latency-serialization bug.

constexpr int H_ = 512;
constexpr int W_ = 512;

__global__ __launch_bounds__(256, 3) void bilateral_kernel(
    const float* __restrict__ x,
    float* __restrict__ out,
    int nthreads)
{
    int t = blockIdx.x * 256 + threadIdx.x;
    if (t >= nthreads) return;

    int qx = t & 127;          // tile col index (4-wide tiles, 128 per row)
    int rg = (t >> 7) & 127;   // tile row index (4-tall tiles, 128 per plane)
    int pl = t >> 14;          // plane (b*C + c), 48 planes
    int w0 = qx << 2;
    int h0 = rg << 2;
    const float* plane = x + ((long)pl << 18);   // 512*512 = 262144
    float* oplane = out + ((long)pl << 18);

    int aL = max(w0 - 2, 0);
    int aR = min(w0 + 4, W_ - 2);
    bool bL = (w0 == 0);
    bool bR = (w0 == W_ - 4);

    // Load the full 8x8 window (rows h0-2 .. h0+5, cols w0-2 .. w0+5).
    float Wn[8][8];
#pragma unroll
    for (int k = 0; k < 8; ++k) {
        int r = h0 + k - 2;
        r = min(abs(r), 2 * (H_ - 1) - r);
        const float* rp = plane + r * W_;
        float2 l2 = *(const float2*)(rp + aL);
        float4 c4 = *(const float4*)(rp + w0);
        float2 r2 = *(const float2*)(rp + aR);
        Wn[k][2] = c4.x; Wn[k][3] = c4.y; Wn[k][4] = c4.z; Wn[k][5] = c4.w;
        Wn[k][0] = bL ? c4.z : l2.x;     // reflect col -2 -> +2
        Wn[k][1] = l2.y;
        Wn[k][6] = r2.x;
        Wn[k][7] = bR ? c4.y : r2.y;     // reflect col 513 -> 509
    }

    const float coef2 = -0.59615498f;    // -log2(e)/(2*1.21)

#pragma unroll
    for (int oi = 0; oi < 4; ++oi) {
        float num[4] = {0.f, 0.f, 0.f, 0.f};
        float den[4] = {0.f, 0.f, 0.f, 0.f};
#pragma unroll
        for (int q = 0; q < 4; ++q) {
            float c = Wn[oi + 2][q + 2];
#pragma unroll
            for (int di = 0; di < 5; ++di) {
#pragma unroll
                for (int dj = 0; dj < 5; ++dj) {
                    float p = Wn[oi + di][q + dj];
                    // compile-time space term
                    float cs = coef2 * (float)((di - 2) * (di - 2) +
                                               (dj - 2) * (dj - 2));
                    float d = p - c;
                    float e = d * coef2;
                    float arg = fmaf(e, d, cs);
                    float w = __builtin_amdgcn_exp2f(arg);
                    num[q] = fmaf(w, p, num[q]);
                    den[q] += w;
                }
            }
        }
        float4 o;
        o.x = num[0] * __builtin_amdgcn_rcpf(den[0]);
        o.y = num[1] * __builtin_amdgcn_rcpf(den[1]);
        o.z = num[2] * __builtin_amdgcn_rcpf(den[2]);
        o.w = num[3] * __builtin_amdgcn_rcpf(den[3]);
        *(float4*)(oplane + (h0 + oi) * W_ + w0) = o;
    }
}

extern "C" void kernel_launch(void* const* d_in, const int* in_sizes, int n_in,
                              void* d_out, int out_size, void* d_ws, size_t ws_size,
                              hipStream_t stream)
{
    const float* x = (const float*)d_in[0];
    float* out = (float*)d_out;
    int nthreads = in_sizes[0] >> 4;         // 16 px per thread -> 786432
    int blocks = (nthreads + 255) / 256;     // 3072 blocks
    bilateral_kernel<<<blocks, 256, 0, stream>>>(x, out, nthreads);
}

// Round 5
// 124.438 us; speedup vs baseline: 1.4002x; 1.1027x over previous
//
#include <hip/hip_runtime.h>

// Bilateral filter, fixed shape: x[16,3,512,512] fp32, K=5, pad=2 reflect.
// sigma_color = sigma_space = 1.1; both normalizations cancel in the ratio.
// Weight folded to one exp2: w = exp2(coef2*d^2 + coef2*sij),
// coef2 = -log2(e)/2.42; coef2*sij is a compile-time constant per tap.
//
// One thread = 4x4 pixel tile; 8x8 register-resident window.
//  - Window is PINNED in VGPRs via empty inline asm after the load block:
//    R3/R4 showed the compiler otherwise minimizes VGPRs (36/44) and
//    serializes load->use chains (53% issue utilization).
//  - Inner math runs on <2 x float> ext-vectors, targeting gfx90a+ packed
//    fp32 (v_pk_fma_f32 etc., full rate): 5 packed VALU + 2 exp per 2 taps
//    = 26 cyc/wave vs 36 scalar. Scalarization fallback is bit-identical.
// Column reflect via 2 cndmask fixups per row (verified R2-R4):
//   w0==0  : col -2 -> x[2]  = c4.z ;  w0==508: col 513 -> x[509] = c4.y
// Row reflect: r = min(abs(r), 2*(H-1)-r).

typedef float v2f __attribute__((ext_vector_type(2)));

constexpr int H_ = 512;
constexpr int W_ = 512;

__global__ __launch_bounds__(256, 4) void bilateral_kernel(
    const float* __restrict__ x,
    float* __restrict__ out,
    int nthreads)
{
    int t = blockIdx.x * 256 + threadIdx.x;
    if (t >= nthreads) return;

    int qx = t & 127;          // tile col index (4-wide tiles)
    int rg = (t >> 7) & 127;   // tile row index (4-tall tiles)
    int pl = t >> 14;          // plane (b*C + c)
    int w0 = qx << 2;
    int h0 = rg << 2;
    const float* plane = x + ((long)pl << 18);   // 512*512
    float* oplane = out + ((long)pl << 18);

    int aL = max(w0 - 2, 0);
    int aR = min(w0 + 4, W_ - 2);
    bool bL = (w0 == 0);
    bool bR = (w0 == W_ - 4);

    // Load full 8x8 window (rows h0-2..h0+5, cols w0-2..w0+5).
    float Wn[8][8];
#pragma unroll
    for (int k = 0; k < 8; ++k) {
        int r = h0 + k - 2;
        r = min(abs(r), 2 * (H_ - 1) - r);
        const float* rp = plane + r * W_;
        float2 l2 = *(const float2*)(rp + aL);
        float4 c4 = *(const float4*)(rp + w0);
        float2 r2 = *(const float2*)(rp + aR);
        Wn[k][2] = c4.x; Wn[k][3] = c4.y; Wn[k][4] = c4.z; Wn[k][5] = c4.w;
        Wn[k][0] = bL ? c4.z : l2.x;   // reflect col -2 -> +2
        Wn[k][1] = l2.y;
        Wn[k][6] = r2.x;
        Wn[k][7] = bR ? c4.y : r2.y;   // reflect col 513 -> 509
    }

    // Pin the window: forces all 64 floats into live VGPRs here, defeating
    // the compiler's min-VGPR rolling-reload restructure.
#pragma unroll
    for (int k = 0; k < 8; ++k)
#pragma unroll
        for (int j = 0; j < 8; ++j)
            asm volatile("" : "+v"(Wn[k][j]));

    const float coef2 = -0.59615498f;  // -log2(e)/(2*1.21)
    const v2f k2 = {coef2, coef2};

#pragma unroll
    for (int oi = 0; oi < 4; ++oi) {
        v2f numA = {0.f, 0.f}, denA = {0.f, 0.f};
        v2f numB = {0.f, 0.f}, denB = {0.f, 0.f};
        v2f cA = {Wn[oi + 2][2], Wn[oi + 2][3]};
        v2f cB = {Wn[oi + 2][4], Wn[oi + 2][5]};
#pragma unroll
        for (int di = 0; di < 5; ++di) {
#pragma unroll
            for (int dj = 0; dj < 5; ++dj) {
                float csf = coef2 * (float)((di - 2) * (di - 2) +
                                            (dj - 2) * (dj - 2));
                v2f cs = {csf, csf};
                v2f pA = {Wn[oi + di][dj],     Wn[oi + di][dj + 1]};
                v2f pB = {Wn[oi + di][dj + 2], Wn[oi + di][dj + 3]};
                v2f dA = pA - cA;
                v2f dB = pB - cB;
                v2f argA = (dA * k2) * dA + cs;   // pk_mul + pk_fma (contract)
                v2f argB = (dB * k2) * dB + cs;
                v2f wA, wB;
                wA.x = __builtin_amdgcn_exp2f(argA.x);
                wA.y = __builtin_amdgcn_exp2f(argA.y);
                wB.x = __builtin_amdgcn_exp2f(argB.x);
                wB.y = __builtin_amdgcn_exp2f(argB.y);
                numA += wA * pA;   // pk_fma
                denA += wA;        // pk_add
                numB += wB * pB;
                denB += wB;
            }
        }
        float4 o;
        o.x = numA.x * __builtin_amdgcn_rcpf(denA.x);
        o.y = numA.y * __builtin_amdgcn_rcpf(denA.y);
        o.z = numB.x * __builtin_amdgcn_rcpf(denB.x);
        o.w = numB.y * __builtin_amdgcn_rcpf(denB.y);
        *(float4*)(oplane + (h0 + oi) * W_ + w0) = o;
    }
}

extern "C" void kernel_launch(void* const* d_in, const int* in_sizes, int n_in,
                              void* d_out, int out_size, void* d_ws, size_t ws_size,
                              hipStream_t stream)
{
    const float* x = (const float*)d_in[0];
    float* out = (float*)d_out;
    int nthreads = in_sizes[0] >> 4;         // 16 px per thread
    int blocks = (nthreads + 255) / 256;
    bilateral_kernel<<<blocks, 256, 0, stream>>>(x, out, nthreads);
}